// Round 1
// baseline (6376.712 us; speedup 1.0000x reference)
//
#include <hip/hip_runtime.h>
#include <hip/hip_bf16.h>
#include <math.h>

// ---------------------------------------------------------------------------
// Round 1: fp32 VALU implementation that EXACTLY simulates the numerics of the
// planned bf16-MFMA design:
//   - hpart[b][n] = b1[n] + sum_d W1[n][1+d]*h[b][d]     (pure fp32, per-b)
//   - y1 = relu(hpart + X*W1x)  -> rounded to bf16       (MFMA A/B input)
//   - W2, W3 rounded to bf16; accumulation fp32          (MFMA semantics)
//   - y2 = relu(.) -> bf16 ; y3 = relu(.) kept fp32      (layer4 from acc)
//   - y4 = W4.y3 + b4 (fp32); f = elu(y4)+1 ; z[b] += cc_w[k]*f*(xmax-x0)/2
// Purpose: validate plumbing (CC table, xmax, row mapping, atomics) and
// MEASURE the bf16 rounding error against the 0.4725 threshold before
// committing to the MFMA layouts. Expect ~0.5-1.2 ms; MFMA rewrite next.
// ws layout (floats): [0..50]=cc_w, [64..114]=steps, [128]=xmax  (<1KB)
// ---------------------------------------------------------------------------

#define B_N    16384
#define KQ     51
#define HD     128
#define IND    64
#define M_TOT  (B_N * KQ)        // 835584
#define TS     64                // samples per tile (M_TOT % TS == 0)
#define NTILES (M_TOT / TS)      // 13056
#define YPITCH (HD + 4)          // fp32 pitch: 16B-aligned rows, bank-spread

__device__ __forceinline__ float bf16_round(float v) {
    __hip_bfloat16 t = __float2bfloat16(v);
    return __bfloat162float(t);
}

__device__ __forceinline__ unsigned pack_bf2(float lo, float hi) {
    __hip_bfloat16 tl = __float2bfloat16(lo);
    __hip_bfloat16 th = __float2bfloat16(hi);
    unsigned ulo = *reinterpret_cast<unsigned short*>(&tl);
    unsigned uhi = *reinterpret_cast<unsigned short*>(&th);
    return ulo | (uhi << 16);
}
__device__ __forceinline__ float unpk_lo(unsigned w) { return __uint_as_float(w << 16); }
__device__ __forceinline__ float unpk_hi(unsigned w) { return __uint_as_float(w & 0xffff0000u); }

// ---------------- prep: CC table (fp64), xmax, zero d_out -------------------
__global__ void umnn_prep(const float* __restrict__ x, float* __restrict__ out,
                          float* __restrict__ ws)
{
    const int tid = threadIdx.x;
    const int bid = blockIdx.x;
    if (bid == 0) {
        if (tid <= KQ - 1) {           // j = 0..50
            int j = tid;
            ws[64 + j] = (float)cos((double)j * M_PI / 50.0);
            double s = 0.0;
            for (int i = 0; i <= 50; ++i) {
                double Wi;
                if (i == 0) Wi = 1.0;
                else if (i & 1) continue;            // odd -> 0
                else Wi = 2.0 / (1.0 - (double)(i * i));
                double lam;
                if (j == 0) lam = 0.5;
                else {
                    lam = cos((double)(i * j) * M_PI / 50.0);
                    if (j == 50) lam *= 0.5;
                }
                lam *= (2.0 / 50.0);
                s += lam * Wi;
            }
            ws[j] = (float)s;
        }
    } else if (bid == 1) {
        __shared__ float red[256];
        float mx = -1e30f;
        for (int i = tid; i < B_N; i += 256) mx = fmaxf(mx, x[i]);
        red[tid] = mx;
        __syncthreads();
        for (int s2 = 128; s2 > 0; s2 >>= 1) {
            if (tid < s2) red[tid] = fmaxf(red[tid], red[tid + s2]);
            __syncthreads();
        }
        if (tid == 0) ws[128] = red[0] + 10.0f;
    } else {
        int i = (bid - 2) * 256 + tid;
        if (i < B_N) out[i] = 0.0f;   // harness poisons d_out; we accumulate
    }
}

// ---------------- main: persistent, 64-sample tiles -------------------------
__launch_bounds__(256, 2)
__global__ void umnn_main(const float* __restrict__ x,  const float* __restrict__ h,
                          const float* __restrict__ W1, const float* __restrict__ b1,
                          const float* __restrict__ W2, const float* __restrict__ b2,
                          const float* __restrict__ W3, const float* __restrict__ b3,
                          const float* __restrict__ W4, const float* __restrict__ b4,
                          float* __restrict__ out, const float* __restrict__ ws)
{
    __shared__ float hpartL[3][HD];
    __shared__ float Y1f[TS][YPITCH];   // y1(bf16-rounded) then y3(fp32)
    __shared__ float Y2f[TS][YPITCH];
    __shared__ float wKl[TS];
    __shared__ float W1xl[HD], b2l[HD], b3l[HD], W4l[HD];

    const int tid = threadIdx.x;
    const int nmy = tid & (HD - 1);
    const int mh  = tid >> 7;           // 0/1

    // W2/W3 rows for feature nmy, bf16-packed, register resident (128 VGPRs)
    unsigned w2p[64], w3p[64];
    {
        const float* r2 = W2 + nmy * HD;
        const float* r3 = W3 + nmy * HD;
        #pragma unroll
        for (int j = 0; j < 64; ++j) {
            w2p[j] = pack_bf2(r2[2 * j], r2[2 * j + 1]);
            w3p[j] = pack_bf2(r3[2 * j], r3[2 * j + 1]);
        }
    }
    if (tid < HD) {
        W1xl[tid] = W1[tid * IND];      // column 0 of W1 (the x weight)
        b2l[tid]  = b2[tid];
        b3l[tid]  = b3[tid];
        W4l[tid]  = W4[tid];
    }
    const float xmax = ws[128];
    const float b4v  = b4[0];

    for (int tile = blockIdx.x; tile < NTILES; tile += gridDim.x) {
        __syncthreads();                // protects LDS reuse across iterations
        const int g0 = tile * TS;
        const int b0 = g0 / KQ;
        const int nb = (g0 + TS - 1) / KQ - b0 + 1;   // <= 3

        // hpart for the <=3 b's in this tile (fp32 exact)
        for (int idx = tid; idx < nb * HD; idx += 256) {
            int bi = idx >> 7, n = idx & (HD - 1);
            int bb = b0 + bi;
            const float* hr = h + bb * (IND - 1);
            const float* wr = W1 + n * IND + 1;
            float acc = b1[n];
            #pragma unroll
            for (int d = 0; d < IND - 1; ++d) acc = fmaf(wr[d], hr[d], acc);
            hpartL[bi][n] = acc;
        }
        __syncthreads();

        // layer 1: y1 = relu(hpart + X*W1x), round to bf16; also wK per row
        #pragma unroll
        for (int it = 0; it < TS * HD / 256; ++it) {
            int idx = tid + it * 256;
            int m = idx >> 7, n = idx & (HD - 1);
            int g  = g0 + m;
            int bb = g / KQ;
            int k  = g - bb * KQ;
            float x0 = x[bb];
            float st = ws[64 + k];
            float X  = fmaf((xmax - x0) * 0.5f, st + 1.0f, x0);
            float v  = fmaf(W1xl[n], X, hpartL[bb - b0][n]);
            Y1f[m][n] = bf16_round(fmaxf(v, 0.0f));
            if (n == 0) wKl[m] = ws[k] * (xmax - x0) * 0.5f;
        }
        __syncthreads();

        // layer 2 (bf16 inputs, fp32 acc) -> Y2 bf16-rounded
        for (int mo = 0; mo < TS / 2; ++mo) {
            int m = 2 * mo + mh;
            const float4* yrow = (const float4*)&Y1f[m][0];
            float acc = b2l[nmy];
            #pragma unroll
            for (int jj = 0; jj < 32; ++jj) {
                float4 y4v = yrow[jj];                 // broadcast read
                unsigned wa = w2p[2 * jj], wb = w2p[2 * jj + 1];
                acc = fmaf(unpk_lo(wa), y4v.x, acc);
                acc = fmaf(unpk_hi(wa), y4v.y, acc);
                acc = fmaf(unpk_lo(wb), y4v.z, acc);
                acc = fmaf(unpk_hi(wb), y4v.w, acc);
            }
            Y2f[m][nmy] = bf16_round(fmaxf(acc, 0.0f));
        }
        __syncthreads();

        // layer 3 -> y3 kept fp32 (layer4 reads "accumulator" precision)
        for (int mo = 0; mo < TS / 2; ++mo) {
            int m = 2 * mo + mh;
            const float4* yrow = (const float4*)&Y2f[m][0];
            float acc = b3l[nmy];
            #pragma unroll
            for (int jj = 0; jj < 32; ++jj) {
                float4 y4v = yrow[jj];
                unsigned wa = w3p[2 * jj], wb = w3p[2 * jj + 1];
                acc = fmaf(unpk_lo(wa), y4v.x, acc);
                acc = fmaf(unpk_hi(wa), y4v.y, acc);
                acc = fmaf(unpk_lo(wb), y4v.z, acc);
                acc = fmaf(unpk_hi(wb), y4v.w, acc);
            }
            Y1f[m][nmy] = fmaxf(acc, 0.0f);            // y3 overwrites y1
        }
        __syncthreads();

        // layer 4 + ELU + quadrature epilogue (wave 0)
        if (tid < TS) {
            int m = tid;
            const float4* yrow = (const float4*)&Y1f[m][0];
            const float4* wrow = (const float4*)&W4l[0];
            float acc = 0.0f;
            #pragma unroll
            for (int jj = 0; jj < 32; ++jj) {
                float4 y4v = yrow[jj];
                float4 w4v = wrow[jj];
                acc = fmaf(w4v.x, y4v.x, acc);
                acc = fmaf(w4v.y, y4v.y, acc);
                acc = fmaf(w4v.z, y4v.z, acc);
                acc = fmaf(w4v.w, y4v.w, acc);
            }
            float y4 = acc + b4v;
            float f  = (y4 > 0.0f) ? (y4 + 1.0f) : __expf(y4);  // elu+1
            int g = g0 + m;
            int bb = g / KQ;
            atomicAdd(&out[bb], f * wKl[m]);
        }
    }
}

// ---------------------------------------------------------------------------
extern "C" void kernel_launch(void* const* d_in, const int* in_sizes, int n_in,
                              void* d_out, int out_size, void* d_ws, size_t ws_size,
                              hipStream_t stream)
{
    const float* x  = (const float*)d_in[0];
    const float* h  = (const float*)d_in[1];
    const float* W1 = (const float*)d_in[2];
    const float* b1 = (const float*)d_in[3];
    const float* W2 = (const float*)d_in[4];
    const float* b2 = (const float*)d_in[5];
    const float* W3 = (const float*)d_in[6];
    const float* b3 = (const float*)d_in[7];
    const float* W4 = (const float*)d_in[8];
    const float* b4 = (const float*)d_in[9];
    float* out = (float*)d_out;
    float* ws  = (float*)d_ws;   // needs only ~520B: cc_w/steps/xmax

    umnn_prep<<<2 + (B_N + 255) / 256, 256, 0, stream>>>(x, out, ws);
    umnn_main<<<512, 256, 0, stream>>>(x, h, W1, b1, W2, b2, W3, b3, W4, b4, out, ws);
}

// Round 2
// 260.566 us; speedup vs baseline: 24.4725x; 24.4725x over previous
//
#include <hip/hip_runtime.h>
#include <hip/hip_bf16.h>
#include <math.h>

// ---------------------------------------------------------------------------
// Round 2: bf16 MFMA implementation (numerics validated in round 1: absmax
// 0.125 vs 0.4725 threshold with identical rounding points).
//
// Structure per 64-sample tile (sample = one (b,k) quadrature point):
//   phase A (VALU): Y1[m][n] = bf16(relu(hpart[b(m)][n] + X(m)*W1x[n]))
//                   written sample-major bf16 to LDS, XOR-swizzled 16B chunks
//   layer 2/3 (MFMA 16x16x32): weights = A-operand, REGISTER-RESIDENT frags
//                   (W2/W3 rows are exactly A-layout [n][k], k-contiguous);
//                   activations = B-operand from LDS (sample-major, b128);
//                   D[row=feature][col=sample] -> lane holds 4 consecutive
//                   features at fixed sample -> packed ds_write_b64 straight
//                   into the sample-major layout layer N+1 reads. No transpose.
//   layer 4: stays in registers: pm[mt] = sum relu(y3)*W4 over wave's 32
//                   features, shuffle-reduce across quads, LDS-atomic across
//                   waves, then elu+1, *wK, global atomicAdd(out[b]).
// hpart[b][n] (the h-dependent 63/64 of layer 1) is precomputed once into
// d_ws (8.4 MB). If ws_size is too small, fall back to in-tile recompute
// (identical fp32 fma order -> identical numerics).
// ws floats: [0..50]=cc_w  [64..114]=steps  [128]=xmax  [256..]=hpart
// ---------------------------------------------------------------------------

#define B_N    16384
#define KQ     51
#define HD     128
#define IND    64
#define M_TOT  (B_N * KQ)        // 835584
#define TS     64                // samples per tile
#define NTILES (M_TOT / TS)      // 13056

#define WS_CCW    0
#define WS_STEPS  64
#define WS_XMAX   128
#define WS_HPART  256

typedef __attribute__((ext_vector_type(8))) short short8;
typedef __attribute__((ext_vector_type(4))) float f32x4;

__device__ __forceinline__ unsigned short f2bf(float f) {
    __hip_bfloat16 t = __float2bfloat16(f);
    return *reinterpret_cast<unsigned short*>(&t);
}

// ---------------- prep: CC table (fp64), xmax, zero d_out -------------------
__global__ void umnn_prep(const float* __restrict__ x, float* __restrict__ out,
                          float* __restrict__ ws)
{
    const int tid = threadIdx.x;
    const int bid = blockIdx.x;
    if (bid == 0) {
        if (tid <= KQ - 1) {
            int j = tid;
            ws[WS_STEPS + j] = (float)cos((double)j * M_PI / 50.0);
            double s = 0.0;
            for (int i = 0; i <= 50; ++i) {
                double Wi;
                if (i == 0) Wi = 1.0;
                else if (i & 1) continue;
                else Wi = 2.0 / (1.0 - (double)(i * i));
                double lam;
                if (j == 0) lam = 0.5;
                else {
                    lam = cos((double)(i * j) * M_PI / 50.0);
                    if (j == 50) lam *= 0.5;
                }
                lam *= (2.0 / 50.0);
                s += lam * Wi;
            }
            ws[WS_CCW + j] = (float)s;
        }
    } else if (bid == 1) {
        __shared__ float red[256];
        float mx = -1e30f;
        for (int i = tid; i < B_N; i += 256) mx = fmaxf(mx, x[i]);
        red[tid] = mx;
        __syncthreads();
        for (int s2 = 128; s2 > 0; s2 >>= 1) {
            if (tid < s2) red[tid] = fmaxf(red[tid], red[tid + s2]);
            __syncthreads();
        }
        if (tid == 0) ws[WS_XMAX] = red[0] + 10.0f;
    } else {
        int i = (bid - 2) * 256 + tid;
        if (i < B_N) out[i] = 0.0f;
    }
}

// ---------------- hpart precompute: [16384][128] fp32 into ws ---------------
__launch_bounds__(256)
__global__ void umnn_hpart(const float* __restrict__ h, const float* __restrict__ W1,
                           const float* __restrict__ b1, float* __restrict__ ws)
{
    __shared__ float W1s[HD][IND + 1];   // +1 pad: row stride 65 dwords
    __shared__ float hsh[2][IND - 1];
    float* hpartG = ws + WS_HPART;
    const int tid = threadIdx.x;

    for (int i = tid; i < HD * IND / 4; i += 256) {
        float4 v = ((const float4*)W1)[i];
        int r = (i * 4) >> 6, c = (i * 4) & 63;
        W1s[r][c] = v.x; W1s[r][c + 1] = v.y; W1s[r][c + 2] = v.z; W1s[r][c + 3] = v.w;
    }
    const int bloc = tid >> 7, n = tid & 127;
    const float b1v = b1[n];
    for (int it = 0; it < 16; ++it) {
        int bb = blockIdx.x * 32 + it * 2;
        __syncthreads();
        if (tid < 126) {
            int r = tid / 63, d = tid - r * 63;
            hsh[r][d] = h[(bb + r) * (IND - 1) + d];
        }
        __syncthreads();
        float acc = b1v;
        #pragma unroll
        for (int d = 0; d < IND - 1; ++d)
            acc = fmaf(W1s[n][1 + d], hsh[bloc][d], acc);
        hpartG[(bb + bloc) * HD + n] = acc;
    }
}

// ---------------- main MFMA kernel ------------------------------------------
template<bool HPG>
__launch_bounds__(256, 2)
__global__ void umnn_main(const float* __restrict__ x,  const float* __restrict__ h,
                          const float* __restrict__ W1, const float* __restrict__ b1,
                          const float* __restrict__ W2, const float* __restrict__ b2,
                          const float* __restrict__ W3, const float* __restrict__ b3,
                          const float* __restrict__ W4, const float* __restrict__ b4,
                          float* __restrict__ out, const float* __restrict__ ws)
{
    __shared__ __align__(16) char  y1s[TS * 256];   // 64 rows x 128 bf16, swizzled
    __shared__ __align__(16) char  y2s[TS * 256];
    __shared__ __align__(16) float hpS[3 * HD];
    __shared__ float Xs[TS], wKs[TS], partS[TS];
    __shared__ int   bIdxS[TS];
    __shared__ float sSteps[KQ], sCcw[KQ];

    const int tid  = threadIdx.x;
    const int w    = tid >> 6;
    const int lane = tid & 63;
    const int q    = lane >> 4;
    const int lm   = lane & 15;
    const int swz  = lm & 7;
    const int ng   = tid & 3;           // phase-A n-block

    if (tid < KQ) { sSteps[tid] = ws[WS_STEPS + tid]; sCcw[tid] = ws[WS_CCW + tid]; }

    const float xmax = ws[WS_XMAX];
    const float b4v  = b4[0];

    // per-thread W1 x-column slice (tile-invariant)
    float w1x[32];
    #pragma unroll
    for (int j = 0; j < 32; ++j) w1x[j] = W1[(ng * 32 + j) * IND];

    // wave-resident weight A-frags + per-lane bias/W4 slices
    short8 W2A[2][4], W3A[2][4];
    f32x4  b2r[2], b3r[2], W4r[2];
    #pragma unroll
    for (int ntl = 0; ntl < 2; ++ntl) {
        const int nf = (w * 2 + ntl) * 16 + lm;       // feature row of A
        #pragma unroll
        for (int kk = 0; kk < 4; ++kk) {
            const float* p2 = W2 + nf * HD + kk * 32 + q * 8;
            const float* p3 = W3 + nf * HD + kk * 32 + q * 8;
            short8 a2, a3;
            #pragma unroll
            for (int j = 0; j < 8; ++j) {
                a2[j] = (short)f2bf(p2[j]);
                a3[j] = (short)f2bf(p3[j]);
            }
            W2A[ntl][kk] = a2; W3A[ntl][kk] = a3;
        }
        const int nb0 = (w * 2 + ntl) * 16 + q * 4;   // lane's 4 C features
        b2r[ntl] = *(const f32x4*)(b2 + nb0);
        b3r[ntl] = *(const f32x4*)(b3 + nb0);
        W4r[ntl] = *(const f32x4*)(W4 + nb0);
    }

    for (int tile = blockIdx.x; tile < NTILES; tile += gridDim.x) {
        __syncthreads();                               // S1: protect LDS reuse
        const int g0 = tile * TS;
        const int b0 = g0 / KQ;
        const int nb = (g0 + TS - 1) / KQ - b0 + 1;    // <= 3 distinct b rows

        // ---- stage hpart rows + per-sample X/wK/bIdx, zero part[] ----
        if (HPG) {
            const float4* hpG = (const float4*)(ws + WS_HPART + b0 * HD);
            for (int i = tid; i < nb * (HD / 4); i += 256)
                ((float4*)hpS)[i] = hpG[i];
        } else {
            for (int idx = tid; idx < nb * HD; idx += 256) {
                int r = idx >> 7, n = idx & 127;
                const float* hr = h + (b0 + r) * (IND - 1);
                const float* wr = W1 + n * IND + 1;
                float acc = b1[n];
                #pragma unroll
                for (int d = 0; d < IND - 1; ++d) acc = fmaf(wr[d], hr[d], acc);
                hpS[idx] = acc;
            }
        }
        if (tid < TS) {
            int g  = g0 + tid;
            int bb = g / KQ;
            int k  = g - bb * KQ;
            float x0 = x[bb];
            Xs[tid]   = fmaf((xmax - x0) * 0.5f, sSteps[k] + 1.0f, x0);
            wKs[tid]  = sCcw[k] * (xmax - x0) * 0.5f;
            bIdxS[tid] = bb - b0;
            partS[tid] = 0.0f;
        }
        __syncthreads();                               // S2

        // ---- phase A: Y1 -> LDS (bf16, sample-major, swizzled) ----
        {
            const int   m  = tid >> 2;
            const float X  = Xs[m];
            const float* hpRow = hpS + bIdxS[m] * HD + ng * 32;
            char* ybase = y1s + m * 256;
            const int wsz = m & 7;
            #pragma unroll
            for (int cc = 0; cc < 4; ++cc) {
                f32x4 ha = *(const f32x4*)(hpRow + cc * 8);
                f32x4 hb = *(const f32x4*)(hpRow + cc * 8 + 4);
                unsigned u0 = (unsigned)f2bf(fmaxf(fmaf(X, w1x[cc*8+0], ha[0]), 0.f))
                            | ((unsigned)f2bf(fmaxf(fmaf(X, w1x[cc*8+1], ha[1]), 0.f)) << 16);
                unsigned u1 = (unsigned)f2bf(fmaxf(fmaf(X, w1x[cc*8+2], ha[2]), 0.f))
                            | ((unsigned)f2bf(fmaxf(fmaf(X, w1x[cc*8+3], ha[3]), 0.f)) << 16);
                unsigned u2 = (unsigned)f2bf(fmaxf(fmaf(X, w1x[cc*8+4], hb[0]), 0.f))
                            | ((unsigned)f2bf(fmaxf(fmaf(X, w1x[cc*8+5], hb[1]), 0.f)) << 16);
                unsigned u3 = (unsigned)f2bf(fmaxf(fmaf(X, w1x[cc*8+6], hb[2]), 0.f))
                            | ((unsigned)f2bf(fmaxf(fmaf(X, w1x[cc*8+7], hb[3]), 0.f)) << 16);
                *(int4*)(ybase + (((ng * 4 + cc) ^ wsz) << 4)) = make_int4(u0, u1, u2, u3);
            }
        }
        __syncthreads();                               // S3

        // ---- layer 2: C = W2(A,reg) x Y1(B,LDS) + b2 ----
        f32x4 C[2][4];
        #pragma unroll
        for (int ntl = 0; ntl < 2; ++ntl)
            #pragma unroll
            for (int mt = 0; mt < 4; ++mt) C[ntl][mt] = b2r[ntl];
        #pragma unroll
        for (int kk = 0; kk < 4; ++kk) {
            short8 Bf[4];
            #pragma unroll
            for (int mt = 0; mt < 4; ++mt)
                Bf[mt] = *(const short8*)(y1s + (mt * 16 + lm) * 256
                                          + ((((kk << 2) + q) ^ swz) << 4));
            #pragma unroll
            for (int ntl = 0; ntl < 2; ++ntl)
                #pragma unroll
                for (int mt = 0; mt < 4; ++mt)
                    C[ntl][mt] = __builtin_amdgcn_mfma_f32_16x16x32_bf16(
                        W2A[ntl][kk], Bf[mt], C[ntl][mt], 0, 0, 0);
        }
        // write Y2 = bf16(relu(C)) packed b64, sample-major
        #pragma unroll
        for (int ntl = 0; ntl < 2; ++ntl) {
            const int cch  = ((w * 2 + ntl) << 1) + (q >> 1);
            const int off8 = (q & 1) << 3;
            #pragma unroll
            for (int mt = 0; mt < 4; ++mt) {
                f32x4 v = C[ntl][mt];
                unsigned lo = (unsigned)f2bf(fmaxf(v[0], 0.f))
                            | ((unsigned)f2bf(fmaxf(v[1], 0.f)) << 16);
                unsigned hi = (unsigned)f2bf(fmaxf(v[2], 0.f))
                            | ((unsigned)f2bf(fmaxf(v[3], 0.f)) << 16);
                *(int2*)(y2s + (mt * 16 + lm) * 256 + ((cch ^ swz) << 4) + off8)
                    = make_int2((int)lo, (int)hi);
            }
        }
        __syncthreads();                               // S4

        // ---- layer 3: C = W3(A,reg) x Y2(B,LDS) + b3 ----
        #pragma unroll
        for (int ntl = 0; ntl < 2; ++ntl)
            #pragma unroll
            for (int mt = 0; mt < 4; ++mt) C[ntl][mt] = b3r[ntl];
        #pragma unroll
        for (int kk = 0; kk < 4; ++kk) {
            short8 Bf[4];
            #pragma unroll
            for (int mt = 0; mt < 4; ++mt)
                Bf[mt] = *(const short8*)(y2s + (mt * 16 + lm) * 256
                                          + ((((kk << 2) + q) ^ swz) << 4));
            #pragma unroll
            for (int ntl = 0; ntl < 2; ++ntl)
                #pragma unroll
                for (int mt = 0; mt < 4; ++mt)
                    C[ntl][mt] = __builtin_amdgcn_mfma_f32_16x16x32_bf16(
                        W3A[ntl][kk], Bf[mt], C[ntl][mt], 0, 0, 0);
        }

        // ---- layer 4 epilogue in registers: pm = sum relu(y3)*W4 ----
        float pm[4] = {0.f, 0.f, 0.f, 0.f};
        #pragma unroll
        for (int ntl = 0; ntl < 2; ++ntl)
            #pragma unroll
            for (int mt = 0; mt < 4; ++mt) {
                f32x4 v = C[ntl][mt];
                pm[mt] = fmaf(fmaxf(v[0], 0.f), W4r[ntl][0], pm[mt]);
                pm[mt] = fmaf(fmaxf(v[1], 0.f), W4r[ntl][1], pm[mt]);
                pm[mt] = fmaf(fmaxf(v[2], 0.f), W4r[ntl][2], pm[mt]);
                pm[mt] = fmaf(fmaxf(v[3], 0.f), W4r[ntl][3], pm[mt]);
            }
        #pragma unroll
        for (int mt = 0; mt < 4; ++mt) {
            float p = pm[mt];
            p += __shfl_xor(p, 16);
            p += __shfl_xor(p, 32);
            if (lane < 16) atomicAdd(&partS[mt * 16 + lane], p);
        }
        __syncthreads();                               // S5

        if (tid < TS) {
            int g  = g0 + tid;
            int bb = g / KQ;
            float y4 = partS[tid] + b4v;
            float f  = (y4 > 0.f) ? (y4 + 1.f) : __expf(y4);
            atomicAdd(&out[bb], f * wKs[tid]);
        }
    }
}

// ---------------------------------------------------------------------------
extern "C" void kernel_launch(void* const* d_in, const int* in_sizes, int n_in,
                              void* d_out, int out_size, void* d_ws, size_t ws_size,
                              hipStream_t stream)
{
    const float* x  = (const float*)d_in[0];
    const float* h  = (const float*)d_in[1];
    const float* W1 = (const float*)d_in[2];
    const float* b1 = (const float*)d_in[3];
    const float* W2 = (const float*)d_in[4];
    const float* b2 = (const float*)d_in[5];
    const float* W3 = (const float*)d_in[6];
    const float* b3 = (const float*)d_in[7];
    const float* W4 = (const float*)d_in[8];
    const float* b4 = (const float*)d_in[9];
    float* out = (float*)d_out;
    float* ws  = (float*)d_ws;

    umnn_prep<<<2 + (B_N + 255) / 256, 256, 0, stream>>>(x, out, ws);

    const size_t need = (size_t)(WS_HPART + B_N * HD) * sizeof(float);
    if (ws_size >= need) {
        umnn_hpart<<<512, 256, 0, stream>>>(h, W1, b1, ws);
        umnn_main<true><<<512, 256, 0, stream>>>(x, h, W1, b1, W2, b2, W3, b3,
                                                 W4, b4, out, ws);
    } else {
        umnn_main<false><<<512, 256, 0, stream>>>(x, h, W1, b1, W2, b2, W3, b3,
                                                  W4, b4, out, ws);
    }
}